// Round 8
// baseline (274.124 us; speedup 1.0000x reference)
//
#include <hip/hip_runtime.h>
#include <hip/hip_bf16.h>

#define HEADS 16
#define SEQ   2048
#define EMB   1024
#define BATCH 2
#define DHEAD 64
#define MTOK  (BATCH * SEQ)   // 4096

typedef __bf16 bf16x8 __attribute__((ext_vector_type(8)));
typedef float  floatx4 __attribute__((ext_vector_type(4)));

__device__ __forceinline__ void gl_lds16(const void* g, void* l) {
  // async global->LDS, 16B/lane; LDS dest = wave-uniform base + lane*16
  __builtin_amdgcn_global_load_lds((__attribute__((address_space(1))) void*)(g),
                                   (__attribute__((address_space(3))) void*)(l), 16, 0, 0);
}

__device__ __forceinline__ unsigned short f2bf(float f) {
  __bf16 h = (__bf16)f;                      // native cvt, RNE
  return __builtin_bit_cast(unsigned short, h);
}

// ---------------- fp32 -> bf16 conversion (x + 4 weights) ----------------
__global__ __launch_bounds__(256) void cvt_kernel(
    const float* __restrict__ x,  const float* __restrict__ wq,
    const float* __restrict__ wk, const float* __restrict__ wv,
    const float* __restrict__ wu,
    unsigned short* __restrict__ xb,  unsigned short* __restrict__ wqb,
    unsigned short* __restrict__ wkb, unsigned short* __restrict__ wvb,
    unsigned short* __restrict__ wub) {
  const int g = blockIdx.x * 256 + threadIdx.x;  // granule of 4 floats
  const int XG = (MTOK * EMB) / 4;               // 1048576
  const int WG = (EMB * EMB) / 4;                // 262144
  const float* src; unsigned short* dst; int off;
  if (g < XG) { src = x; dst = xb; off = g; }
  else {
    int t = g - XG; int wsel = t / WG; off = t - wsel * WG;
    const float* ss[4] = {wq, wk, wv, wu};
    unsigned short* dd[4] = {wqb, wkb, wvb, wub};
    src = ss[wsel]; dst = dd[wsel];
  }
  float4 v = ((const float4*)src)[off];
  ushort4 o;
  o.x = f2bf(v.x); o.y = f2bf(v.y); o.z = f2bf(v.z); o.w = f2bf(v.w);
  ((ushort4*)dst)[off] = o;
}

// ---------------- FUSED QKV projection: q,k,v = x @ {Wq,Wk,Wv}^T ----------------
// BM=128, BN=64, BK=64, one block computes Q/K/V tiles for the same (m0,n0):
// x staged ONCE per k-iter for 3 outputs -> 48 MFMA/wave per barrier.
__global__ __launch_bounds__(256) void gemm_qkv(
    const unsigned short* __restrict__ xb,
    const unsigned short* __restrict__ wqb, const unsigned short* __restrict__ wkb,
    const unsigned short* __restrict__ wvb,
    unsigned short* __restrict__ Qb, unsigned short* __restrict__ Kb,
    unsigned short* __restrict__ Vt) {
  constexpr int BM = 128, BN = 64, BK = 64;
  __shared__ unsigned short As[BM * BK];        // XOR-swizzled rows
  __shared__ unsigned short Bs[3 * BN * BK];
  const int m0 = blockIdx.x * BM, n0 = blockIdx.y * BN;
  const int tid = threadIdx.x, w = tid >> 6, lane = tid & 63;
  const int quad = lane >> 4, l16 = lane & 15;
  const int wm = w >> 1, wn = w & 1;
  const int srow = lane >> 3;
  const int scol = ((lane & 7) ^ srow) * 8;
  const unsigned short* Ws[3] = {wqb, wkb, wvb};

  floatx4 acc[3][4][2] = {};

  for (int kt = 0; kt < EMB / BK; ++kt) {
    const int k0 = kt * BK;
#pragma unroll
    for (int i = 0; i < 4; ++i) {
      int r0 = i * 32 + w * 8;
      gl_lds16(xb + (size_t)(m0 + r0 + srow) * EMB + k0 + scol, &As[r0 * BK]);
    }
#pragma unroll
    for (int z = 0; z < 3; ++z)
#pragma unroll
      for (int i = 0; i < 2; ++i) {
        int r0 = i * 32 + w * 8;
        gl_lds16(Ws[z] + (size_t)(n0 + r0 + srow) * EMB + k0 + scol,
                 &Bs[z * (BN * BK) + r0 * BK]);
      }
    __syncthreads();
#pragma unroll
    for (int ks = 0; ks < 2; ++ks) {
      bf16x8 af[4];
#pragma unroll
      for (int mb = 0; mb < 4; ++mb) {
        int ra = wm * 64 + mb * 16 + l16;
        af[mb] = *(const bf16x8*)&As[ra * BK + (((ks * 4 + quad) ^ (ra & 7)) * 8)];
      }
#pragma unroll
      for (int z = 0; z < 3; ++z) {
        bf16x8 bfv[2];
#pragma unroll
        for (int nb = 0; nb < 2; ++nb) {
          int rb = wn * 32 + nb * 16 + l16;
          bfv[nb] = *(const bf16x8*)&Bs[z * (BN * BK) + rb * BK + (((ks * 4 + quad) ^ (rb & 7)) * 8)];
        }
#pragma unroll
        for (int mb = 0; mb < 4; ++mb)
#pragma unroll
          for (int nb = 0; nb < 2; ++nb)
            acc[z][mb][nb] = __builtin_amdgcn_mfma_f32_16x16x32_bf16(af[mb], bfv[nb], acc[z][mb][nb], 0, 0, 0);
      }
    }
    __syncthreads();
  }

  // ---- epilogue: Q (scaled), K, V^T ----
#pragma unroll
  for (int z = 0; z < 2; ++z) {
    unsigned short* C = (z == 0) ? Qb : Kb;
    const float scale = (z == 0) ? 0.180336876f : 1.0f;  // 0.125*log2(e) folded into Q
#pragma unroll
    for (int mb = 0; mb < 4; ++mb) {
#pragma unroll
      for (int nb = 0; nb < 2; ++nb) {
        int n = n0 + wn * 32 + nb * 16 + l16;
#pragma unroll
        for (int r = 0; r < 4; ++r) {
          int m = m0 + wm * 64 + mb * 16 + quad * 4 + r;
          C[(size_t)m * EMB + n] = f2bf(acc[z][mb][nb][r] * scale);
        }
      }
    }
  }
#pragma unroll
  for (int mb = 0; mb < 4; ++mb) {
    int mbase = m0 + wm * 64 + mb * 16 + quad * 4;
    int b = mbase >> 11, s = mbase & (SEQ - 1);
#pragma unroll
    for (int nb = 0; nb < 2; ++nb) {
      int n = n0 + wn * 32 + nb * 16 + l16;
      ushort4 o;
      o.x = f2bf(acc[2][mb][nb][0]); o.y = f2bf(acc[2][mb][nb][1]);
      o.z = f2bf(acc[2][mb][nb][2]); o.w = f2bf(acc[2][mb][nb][3]);
      *(ushort4*)&Vt[((size_t)b * (HEADS * DHEAD) + n) * SEQ + s] = o;
    }
  }
}

// ---------------- flash-style causal attention, v7: barrier-free ----------------
// Each WAVE independently handles 16 q-rows. K/V MFMA B-fragments are loaded
// DIRECTLY global->VGPR (lane (l16,quad) reads 16 contiguous bytes of row
// nb*16+l16) — no LDS staging, no __syncthreads anywhere. Only LDS use is the
// wave-private P round-trip. Fixed-shift softmax (exact, see R5). vf loads
// issue before the exp2 block so they complete under softmax VALU.
// Block = 4 consecutive row-groups of one bh (shared K/V stream -> L1 reuse).
// 1D grid 1024, globally big-first (rg = 127 - ...).
__global__ __launch_bounds__(256) void attn_kernel(
    const unsigned short* __restrict__ Qb, const unsigned short* __restrict__ Kb,
    const unsigned short* __restrict__ Vt, unsigned short* __restrict__ ctx) {
  constexpr int PST = 76;                         // zero conflicts measured (R6)
  __shared__ __bf16 Ps[4 * 16 * PST];             // per-wave [16 qrows][PST keys]
  const int g = blockIdx.x;
  const int bh = g & 31;
  const int b = bh >> 4, h = bh & 15;
  const int tid = threadIdx.x, w = tid >> 6, lane = tid & 63;
  const int quad = lane >> 4, l16 = lane & 15;
  const int rg = 127 - ((g >> 5) * 4 + w);        // row-group 0..127, big first
  const int nkt = (rg >> 2) + 1;                  // causal KT=64 tiles

  const unsigned short* Kbh = Kb + (size_t)b * SEQ * EMB + h * DHEAD;
  const unsigned short* Vbh = Vt + (size_t)bh * DHEAD * SEQ;
  __bf16* Pw = &Ps[w * (16 * PST)];

  const int myrow = rg * 16 + quad * 4;           // this lane's 4 acc rows start
  const size_t qoff = (size_t)(b * SEQ + rg * 16 + l16) * EMB + h * DHEAD;
  bf16x8 qf[2];
  qf[0] = *(const bf16x8*)&Qb[qoff + quad * 8];
  qf[1] = *(const bf16x8*)&Qb[qoff + 32 + quad * 8];

  float lsum[4] = {0.0f, 0.0f, 0.0f, 0.0f};
  floatx4 acc_o[4] = {};

  for (int kt = 0; kt < nkt; ++kt) {
    const int kt0 = kt * 64;
    // ---- K fragments: direct global->VGPR (B-frag: row nb*16+l16, 16B/lane) ----
    const unsigned short* Kt = Kbh + (size_t)(kt0 + l16) * EMB + quad * 8;
    bf16x8 kf[8];
#pragma unroll
    for (int ks = 0; ks < 2; ++ks)
#pragma unroll
      for (int nb = 0; nb < 4; ++nb)
        kf[ks * 4 + nb] = *(const bf16x8*)(Kt + (size_t)nb * (16 * EMB) + ks * 32);

    // ---- S = Q K^T : 16 rows x 64 keys ----
    floatx4 accs[4] = {};
#pragma unroll
    for (int ks = 0; ks < 2; ++ks)
#pragma unroll
      for (int nb = 0; nb < 4; ++nb)
        accs[nb] = __builtin_amdgcn_mfma_f32_16x16x32_bf16(qf[ks], kf[ks * 4 + nb], accs[nb], 0, 0, 0);

    // ---- V fragments issued now; complete under the softmax VALU below ----
    const unsigned short* Vt0 = Vbh + (size_t)l16 * SEQ + kt0 + quad * 8;
    bf16x8 vf[8];
#pragma unroll
    for (int ks = 0; ks < 2; ++ks)
#pragma unroll
      for (int nb = 0; nb < 4; ++nb)
        vf[ks * 4 + nb] = *(const bf16x8*)(Vt0 + (size_t)nb * (16 * SEQ) + ks * 32);

    // ---- causal mask (final tile only) ----
    if (kt == nkt - 1) {
#pragma unroll
      for (int nb = 0; nb < 4; ++nb) {
        int col = kt0 + nb * 16 + l16;
#pragma unroll
        for (int r = 0; r < 4; ++r)
          if (col > myrow + r) accs[nb][r] = -1e30f;
      }
    }

    // ---- p = exp2(s) (fixed shift), accumulate l, stash P (wave-private) ----
#pragma unroll
    for (int r = 0; r < 4; ++r)
#pragma unroll
      for (int nb = 0; nb < 4; ++nb) {
        float pe = exp2f(accs[nb][r]);
        Pw[(quad * 4 + r) * PST + nb * 16 + l16] = (__bf16)pe;
        lsum[r] += pe;
      }

    // ---- O += P V ----
#pragma unroll
    for (int ks = 0; ks < 2; ++ks) {
      bf16x8 pf = *(const bf16x8*)&Pw[l16 * PST + ks * 32 + quad * 8];
#pragma unroll
      for (int nb = 0; nb < 4; ++nb)
        acc_o[nb] = __builtin_amdgcn_mfma_f32_16x16x32_bf16(pf, vf[ks * 4 + nb], acc_o[nb], 0, 0, 0);
    }
  }

  // ---- reduce l over the 16-lane group (disjoint key subsets), then write ----
#pragma unroll
  for (int r = 0; r < 4; ++r) {
    float rs = lsum[r];
    rs += __shfl_xor(rs, 1);
    rs += __shfl_xor(rs, 2);
    rs += __shfl_xor(rs, 4);
    rs += __shfl_xor(rs, 8);
    float inv = 1.0f / rs;
    size_t base = (size_t)(b * SEQ + myrow + r) * EMB + h * DHEAD;
#pragma unroll
    for (int nb = 0; nb < 4; ++nb)
      ctx[base + nb * 16 + l16] = f2bf(acc_o[nb][r] * inv);
  }
}

// ---------------- output projection: out = ctx @ Wu^T + bu (fp32 out) ----------------
// 128x64 tile, BK=64 swizzled; 512 blocks; wave tile 64x32 (4x2 MFMA grid).
__global__ __launch_bounds__(256) void gemm_out(
    const unsigned short* __restrict__ ctx, const unsigned short* __restrict__ wub,
    const float* __restrict__ bu, float* __restrict__ out) {
  constexpr int BM = 128, BN = 64, BK = 64;
  __shared__ unsigned short As[BM * BK];
  __shared__ unsigned short Bs[BN * BK];
  const int m0 = blockIdx.x * BM, n0 = blockIdx.y * BN;
  const int tid = threadIdx.x, w = tid >> 6, lane = tid & 63;
  const int quad = lane >> 4, l16 = lane & 15;
  const int wm = w >> 1, wn = w & 1;
  const int srow = lane >> 3;
  const int scol = ((lane & 7) ^ srow) * 8;

  floatx4 acc[4][2] = {};

  for (int kt = 0; kt < EMB / BK; ++kt) {
    const int k0 = kt * BK;
#pragma unroll
    for (int i = 0; i < 4; ++i) {
      int r0 = i * 32 + w * 8;
      gl_lds16(ctx + (size_t)(m0 + r0 + srow) * EMB + k0 + scol, &As[r0 * BK]);
    }
#pragma unroll
    for (int i = 0; i < 2; ++i) {
      int r0 = i * 32 + w * 8;
      gl_lds16(wub + (size_t)(n0 + r0 + srow) * EMB + k0 + scol, &Bs[r0 * BK]);
    }
    __syncthreads();
    bf16x8 af[4][2], bfv[2][2];
#pragma unroll
    for (int mb = 0; mb < 4; ++mb) {
      int ra = wm * 64 + mb * 16 + l16;
#pragma unroll
      for (int ks = 0; ks < 2; ++ks)
        af[mb][ks] = *(const bf16x8*)&As[ra * BK + (((ks * 4 + quad) ^ (ra & 7)) * 8)];
    }
#pragma unroll
    for (int nb = 0; nb < 2; ++nb) {
      int rb = wn * 32 + nb * 16 + l16;
#pragma unroll
      for (int ks = 0; ks < 2; ++ks)
        bfv[nb][ks] = *(const bf16x8*)&Bs[rb * BK + (((ks * 4 + quad) ^ (rb & 7)) * 8)];
    }
#pragma unroll
    for (int ks = 0; ks < 2; ++ks)
#pragma unroll
      for (int mb = 0; mb < 4; ++mb)
#pragma unroll
        for (int nb = 0; nb < 2; ++nb)
          acc[mb][nb] = __builtin_amdgcn_mfma_f32_16x16x32_bf16(af[mb][ks], bfv[nb][ks], acc[mb][nb], 0, 0, 0);
    __syncthreads();
  }

#pragma unroll
  for (int mb = 0; mb < 4; ++mb) {
#pragma unroll
    for (int nb = 0; nb < 2; ++nb) {
      int n = n0 + wn * 32 + nb * 16 + l16;
      float bias = bu[n];
#pragma unroll
      for (int r = 0; r < 4; ++r) {
        int m = m0 + wm * 64 + mb * 16 + quad * 4 + r;
        out[(size_t)m * EMB + n] = acc[mb][nb][r] + bias;
      }
    }
  }
}

extern "C" void kernel_launch(void* const* d_in, const int* in_sizes, int n_in,
                              void* d_out, int out_size, void* d_ws, size_t ws_size,
                              hipStream_t stream) {
  // setup_inputs order: x, Wk, Wq, Wv, Wu, bu
  const float* x  = (const float*)d_in[0];
  const float* Wk = (const float*)d_in[1];
  const float* Wq = (const float*)d_in[2];
  const float* Wv = (const float*)d_in[3];
  const float* Wu = (const float*)d_in[4];
  const float* bu = (const float*)d_in[5];

  char* ws = (char*)d_ws;
  const size_t MB1 = 1 << 20;
  unsigned short* xb  = (unsigned short*)(ws + 0);
  unsigned short* wqb = (unsigned short*)(ws + 8  * MB1);
  unsigned short* wkb = (unsigned short*)(ws + 10 * MB1);
  unsigned short* wvb = (unsigned short*)(ws + 12 * MB1);
  unsigned short* wub = (unsigned short*)(ws + 14 * MB1);
  unsigned short* Qb  = (unsigned short*)(ws + 16 * MB1);
  unsigned short* Kb  = (unsigned short*)(ws + 24 * MB1);
  unsigned short* Vt  = (unsigned short*)(ws + 32 * MB1);
  unsigned short* ctx = (unsigned short*)(ws + 40 * MB1);

  cvt_kernel<<<8192, 256, 0, stream>>>(x, Wq, Wk, Wv, Wu, xb, wqb, wkb, wvb, wub);
  gemm_qkv<<<dim3(32, 16), 256, 0, stream>>>(xb, wqb, wkb, wvb, Qb, Kb, Vt);
  attn_kernel<<<1024, 256, 0, stream>>>(Qb, Kb, Vt, ctx);
  gemm_out<<<dim3(32, 16), 256, 0, stream>>>(ctx, wub, bu, (float*)d_out);
}

// Round 9
// 200.703 us; speedup vs baseline: 1.3658x; 1.3658x over previous
//
#include <hip/hip_runtime.h>
#include <hip/hip_bf16.h>

#define HEADS 16
#define SEQ   2048
#define EMB   1024
#define BATCH 2
#define DHEAD 64
#define MTOK  (BATCH * SEQ)   // 4096

typedef __bf16 bf16x8 __attribute__((ext_vector_type(8)));
typedef float  floatx4 __attribute__((ext_vector_type(4)));

__device__ __forceinline__ void gl_lds16(const void* g, void* l) {
  // async global->LDS, 16B/lane; LDS dest = wave-uniform base + lane*16
  __builtin_amdgcn_global_load_lds((__attribute__((address_space(1))) void*)(g),
                                   (__attribute__((address_space(3))) void*)(l), 16, 0, 0);
}

__device__ __forceinline__ unsigned short f2bf(float f) {
  __bf16 h = (__bf16)f;                      // native cvt, RNE
  return __builtin_bit_cast(unsigned short, h);
}

// ---------------- fp32 -> bf16 conversion (x + 4 weights) ----------------
__global__ __launch_bounds__(256) void cvt_kernel(
    const float* __restrict__ x,  const float* __restrict__ wq,
    const float* __restrict__ wk, const float* __restrict__ wv,
    const float* __restrict__ wu,
    unsigned short* __restrict__ xb,  unsigned short* __restrict__ wqb,
    unsigned short* __restrict__ wkb, unsigned short* __restrict__ wvb,
    unsigned short* __restrict__ wub) {
  const int g = blockIdx.x * 256 + threadIdx.x;  // granule of 4 floats
  const int XG = (MTOK * EMB) / 4;               // 1048576
  const int WG = (EMB * EMB) / 4;                // 262144
  const float* src; unsigned short* dst; int off;
  if (g < XG) { src = x; dst = xb; off = g; }
  else {
    int t = g - XG; int wsel = t / WG; off = t - wsel * WG;
    const float* ss[4] = {wq, wk, wv, wu};
    unsigned short* dd[4] = {wqb, wkb, wvb, wub};
    src = ss[wsel]; dst = dd[wsel];
  }
  float4 v = ((const float4*)src)[off];
  ushort4 o;
  o.x = f2bf(v.x); o.y = f2bf(v.y); o.z = f2bf(v.z); o.w = f2bf(v.w);
  ((ushort4*)dst)[off] = o;
}

// ---------------- FUSED QKV projection, BK=128 ----------------
// BM=128, BN=64, BK=128: 8 k-iters, 96 MFMA/wave per barrier (vs 48 at BK=64).
// LDS 80KB -> 2 blocks/CU (grid 512 = 2/CU anyway). 16-chunk XOR swizzle
// (chunk ^ (row&15)) keeps b128 fragment reads conflict-free.
__global__ __launch_bounds__(256) void gemm_qkv(
    const unsigned short* __restrict__ xb,
    const unsigned short* __restrict__ wqb, const unsigned short* __restrict__ wkb,
    const unsigned short* __restrict__ wvb,
    unsigned short* __restrict__ Qb, unsigned short* __restrict__ Kb,
    unsigned short* __restrict__ Vt) {
  constexpr int BM = 128, BN = 64, BK = 128;
  __shared__ unsigned short As[BM * BK];        // 32 KB
  __shared__ unsigned short Bs[3 * BN * BK];    // 48 KB
  const int m0 = blockIdx.x * BM, n0 = blockIdx.y * BN;
  const int tid = threadIdx.x, w = tid >> 6, lane = tid & 63;
  const int quad = lane >> 4, l16 = lane & 15;
  const int wm = w >> 1, wn = w & 1;
  const int srow = lane >> 4;                   // 0..3 rows per issue
  const int cphys = lane & 15;                  // physical chunk (16B units)
  const unsigned short* Ws[3] = {wqb, wkb, wvb};

  floatx4 acc[3][4][2] = {};

  for (int kt = 0; kt < EMB / BK; ++kt) {
    const int k0 = kt * BK;
    // ---- stage A: 8 issues/wave, 4 rows each ----
#pragma unroll
    for (int i = 0; i < 8; ++i) {
      int r0 = i * 16 + w * 4;
      int scol = (cphys ^ ((r0 + srow) & 15)) * 8;
      gl_lds16(xb + (size_t)(m0 + r0 + srow) * EMB + k0 + scol, &As[r0 * BK]);
    }
    // ---- stage B (3 weights): 12 issues/wave ----
#pragma unroll
    for (int z = 0; z < 3; ++z)
#pragma unroll
      for (int j = 0; j < 4; ++j) {
        int r0 = j * 16 + w * 4;
        int scol = (cphys ^ ((r0 + srow) & 15)) * 8;
        gl_lds16(Ws[z] + (size_t)(n0 + r0 + srow) * EMB + k0 + scol,
                 &Bs[z * (BN * BK) + r0 * BK]);
      }
    __syncthreads();
#pragma unroll
    for (int ks = 0; ks < 4; ++ks) {
      bf16x8 af[4];
#pragma unroll
      for (int mb = 0; mb < 4; ++mb) {
        int ra = wm * 64 + mb * 16 + l16;
        af[mb] = *(const bf16x8*)&As[ra * BK + (((ks * 4 + quad) ^ (ra & 15)) * 8)];
      }
#pragma unroll
      for (int z = 0; z < 3; ++z) {
        bf16x8 bfv[2];
#pragma unroll
        for (int nb = 0; nb < 2; ++nb) {
          int rb = wn * 32 + nb * 16 + l16;
          bfv[nb] = *(const bf16x8*)&Bs[z * (BN * BK) + rb * BK + (((ks * 4 + quad) ^ (rb & 15)) * 8)];
        }
#pragma unroll
        for (int mb = 0; mb < 4; ++mb)
#pragma unroll
          for (int nb = 0; nb < 2; ++nb)
            acc[z][mb][nb] = __builtin_amdgcn_mfma_f32_16x16x32_bf16(af[mb], bfv[nb], acc[z][mb][nb], 0, 0, 0);
      }
    }
    __syncthreads();
  }

  // ---- epilogue: Q (scaled), K, V^T ----
#pragma unroll
  for (int z = 0; z < 2; ++z) {
    unsigned short* C = (z == 0) ? Qb : Kb;
    const float scale = (z == 0) ? 0.180336876f : 1.0f;  // 0.125*log2(e) folded into Q
#pragma unroll
    for (int mb = 0; mb < 4; ++mb) {
#pragma unroll
      for (int nb = 0; nb < 2; ++nb) {
        int n = n0 + wn * 32 + nb * 16 + l16;
#pragma unroll
        for (int r = 0; r < 4; ++r) {
          int m = m0 + wm * 64 + mb * 16 + quad * 4 + r;
          C[(size_t)m * EMB + n] = f2bf(acc[z][mb][nb][r] * scale);
        }
      }
    }
  }
#pragma unroll
  for (int mb = 0; mb < 4; ++mb) {
    int mbase = m0 + wm * 64 + mb * 16 + quad * 4;
    int b = mbase >> 11, s = mbase & (SEQ - 1);
#pragma unroll
    for (int nb = 0; nb < 2; ++nb) {
      int n = n0 + wn * 32 + nb * 16 + l16;
      ushort4 o;
      o.x = f2bf(acc[2][mb][nb][0]); o.y = f2bf(acc[2][mb][nb][1]);
      o.z = f2bf(acc[2][mb][nb][2]); o.w = f2bf(acc[2][mb][nb][3]);
      *(ushort4*)&Vt[((size_t)b * (HEADS * DHEAD) + n) * SEQ + s] = o;
    }
  }
}

// ---------------- flash-style causal attention (R5 version, 66.8 us) ----------------
// QT=64, KT=128, paired grid (16,32): uniform 17 k-tiles/block. Fixed-shift
// softmax (exact — scores bounded, see R5). Fragment-ordered K/V staging.
__global__ __launch_bounds__(256) void attn_kernel(
    const unsigned short* __restrict__ Qb, const unsigned short* __restrict__ Kb,
    const unsigned short* __restrict__ Vt, unsigned short* __restrict__ ctx) {
  constexpr int KT = 128;
  constexpr int PST = KT + 8;                     // padded row stride (ushorts)
  __shared__ unsigned short Ks[KT * DHEAD];       // fragment order: (f*64+lane)*8
  __shared__ unsigned short Vs[DHEAD * KT];       // fragment order
  __shared__ __bf16 Ps[4 * 16 * PST];             // per-wave [16][PST]
  const int pair = blockIdx.x, bh = blockIdx.y;
  const int b = bh >> 4, h = bh & 15;
  const int tid = threadIdx.x, w = tid >> 6, lane = tid & 63;
  const int quad = lane >> 4, l16 = lane & 15;

  const unsigned short* Kbh = Kb + (size_t)b * SEQ * EMB + h * DHEAD;
  const unsigned short* Vbh = Vt + (size_t)bh * DHEAD * SEQ;
  __bf16* Pw = &Ps[w * (16 * PST)];

  // per-lane staging coordinates (chunk c = i*256 + tid)
  int kq[4], kd[4], vd[4], vk[4];
#pragma unroll
  for (int i = 0; i < 4; ++i) {
    int c = i * 256 + tid;
    kq[i] = ((c >> 6) & 7) * 16 + (c & 15);           // key row within tile (K)
    kd[i] = ((c >> 9) << 5) + (((c >> 4) & 3) << 3);  // d offset (K)
    vd[i] = (((c >> 6) & 3) << 4) + (c & 15);         // d row (V^T)
    vk[i] = (((c >> 8) & 3) << 5) + (((c >> 4) & 3) << 3);  // key offset (V^T)
  }

  for (int pi = 0; pi < 2; ++pi) {
    const int qt = pi ? (31 - pair) : pair;
    const int q0 = qt * 64;
    const int myrow = q0 + w * 16 + quad * 4;     // this lane's 4 rows start

    const size_t qrow = (size_t)(b * SEQ + q0 + w * 16 + l16) * EMB + h * DHEAD;
    bf16x8 qf[2];
    qf[0] = *(const bf16x8*)&Qb[qrow + quad * 8];
    qf[1] = *(const bf16x8*)&Qb[qrow + 32 + quad * 8];

    float lsum[4] = {0.0f, 0.0f, 0.0f, 0.0f};     // lane-local partial row sums
    floatx4 acc_o[4] = {};

    const int nkt = (qt + 2) >> 1;                // ceil((qt+1)*64/128)
    for (int ktile = 0; ktile < nkt; ++ktile) {
      const int kt0 = ktile * KT;
      // ---- stage K (16KB) + V (16KB) in fragment order ----
#pragma unroll
      for (int i = 0; i < 4; ++i) {
        gl_lds16(Kbh + (size_t)(kt0 + kq[i]) * EMB + kd[i], &Ks[(i * 256 + w * 64) * 8]);
        gl_lds16(Vbh + (size_t)vd[i] * SEQ + kt0 + vk[i], &Vs[(i * 256 + w * 64) * 8]);
      }
      __syncthreads();

      // ---- S = Q K^T : 16 rows x 128 keys per wave ----
      floatx4 accs[8] = {};
#pragma unroll
      for (int ks = 0; ks < 2; ++ks)
#pragma unroll
        for (int nb = 0; nb < 8; ++nb) {
          bf16x8 kf = *(const bf16x8*)&Ks[((ks * 8 + nb) * 64 + lane) * 8];
          accs[nb] = __builtin_amdgcn_mfma_f32_16x16x32_bf16(qf[ks], kf, accs[nb], 0, 0, 0);
        }

      // ---- causal mask (diagonal tile only) ----
      if (ktile == nkt - 1) {
#pragma unroll
        for (int nb = 0; nb < 8; ++nb) {
          int col = kt0 + nb * 16 + l16;
#pragma unroll
          for (int r = 0; r < 4; ++r)
            if (col > myrow + r) accs[nb][r] = -1e30f;
        }
      }

      // ---- p = exp2(s) (fixed shift), accumulate l, stash P ----
#pragma unroll
      for (int r = 0; r < 4; ++r) {
#pragma unroll
        for (int nb = 0; nb < 8; ++nb) {
          float pe = exp2f(accs[nb][r]);
          Pw[(quad * 4 + r) * PST + nb * 16 + l16] = (__bf16)pe;
          lsum[r] += pe;
        }
      }

      // ---- O += P V  (Ps is wave-private: no barrier needed) ----
#pragma unroll
      for (int ks = 0; ks < 4; ++ks) {
        bf16x8 pf = *(const bf16x8*)&Pw[l16 * PST + ks * 32 + quad * 8];
#pragma unroll
        for (int nb = 0; nb < 4; ++nb) {
          bf16x8 vf = *(const bf16x8*)&Vs[((ks * 4 + nb) * 64 + lane) * 8];
          acc_o[nb] = __builtin_amdgcn_mfma_f32_16x16x32_bf16(pf, vf, acc_o[nb], 0, 0, 0);
        }
      }
      __syncthreads();   // all waves done with Ks/Vs before next staging
    }

    // ---- reduce l over the 16-lane group (disjoint key subsets), then write ----
#pragma unroll
    for (int r = 0; r < 4; ++r) {
      float rs = lsum[r];
      rs += __shfl_xor(rs, 1);
      rs += __shfl_xor(rs, 2);
      rs += __shfl_xor(rs, 4);
      rs += __shfl_xor(rs, 8);
      float inv = 1.0f / rs;
      size_t base = (size_t)(b * SEQ + myrow + r) * EMB + h * DHEAD;
#pragma unroll
      for (int nb = 0; nb < 4; ++nb)
        ctx[base + nb * 16 + l16] = f2bf(acc_o[nb][r] * inv);
    }
  }
}

// ---------------- output projection, BK=128: out = ctx @ Wu^T + bu ----------------
// BM=128, BN=64, BK=128: 8 k-iters, 32 MFMA/wave per barrier; LDS 48KB.
__global__ __launch_bounds__(256) void gemm_out(
    const unsigned short* __restrict__ ctx, const unsigned short* __restrict__ wub,
    const float* __restrict__ bu, float* __restrict__ out) {
  constexpr int BM = 128, BN = 64, BK = 128;
  __shared__ unsigned short As[BM * BK];        // 32 KB
  __shared__ unsigned short Bs[BN * BK];        // 16 KB
  const int m0 = blockIdx.x * BM, n0 = blockIdx.y * BN;
  const int tid = threadIdx.x, w = tid >> 6, lane = tid & 63;
  const int quad = lane >> 4, l16 = lane & 15;
  const int wm = w >> 1, wn = w & 1;
  const int srow = lane >> 4;
  const int cphys = lane & 15;

  floatx4 acc[4][2] = {};

  for (int kt = 0; kt < EMB / BK; ++kt) {
    const int k0 = kt * BK;
#pragma unroll
    for (int i = 0; i < 8; ++i) {
      int r0 = i * 16 + w * 4;
      int scol = (cphys ^ ((r0 + srow) & 15)) * 8;
      gl_lds16(ctx + (size_t)(m0 + r0 + srow) * EMB + k0 + scol, &As[r0 * BK]);
    }
#pragma unroll
    for (int j = 0; j < 4; ++j) {
      int r0 = j * 16 + w * 4;
      int scol = (cphys ^ ((r0 + srow) & 15)) * 8;
      gl_lds16(wub + (size_t)(n0 + r0 + srow) * EMB + k0 + scol, &Bs[r0 * BK]);
    }
    __syncthreads();
#pragma unroll
    for (int ks = 0; ks < 4; ++ks) {
      bf16x8 af[4];
#pragma unroll
      for (int mb = 0; mb < 4; ++mb) {
        int ra = wm * 64 + mb * 16 + l16;
        af[mb] = *(const bf16x8*)&As[ra * BK + (((ks * 4 + quad) ^ (ra & 15)) * 8)];
      }
      bf16x8 bfv[2];
#pragma unroll
      for (int nb = 0; nb < 2; ++nb) {
        int rb = wn * 32 + nb * 16 + l16;
        bfv[nb] = *(const bf16x8*)&Bs[rb * BK + (((ks * 4 + quad) ^ (rb & 15)) * 8)];
      }
#pragma unroll
      for (int mb = 0; mb < 4; ++mb)
#pragma unroll
        for (int nb = 0; nb < 2; ++nb)
          acc[mb][nb] = __builtin_amdgcn_mfma_f32_16x16x32_bf16(af[mb], bfv[nb], acc[mb][nb], 0, 0, 0);
    }
    __syncthreads();
  }

#pragma unroll
  for (int mb = 0; mb < 4; ++mb) {
#pragma unroll
    for (int nb = 0; nb < 2; ++nb) {
      int n = n0 + wn * 32 + nb * 16 + l16;
      float bias = bu[n];
#pragma unroll
      for (int r = 0; r < 4; ++r) {
        int m = m0 + wm * 64 + mb * 16 + quad * 4 + r;
        out[(size_t)m * EMB + n] = acc[mb][nb][r] + bias;
      }
    }
  }
}

extern "C" void kernel_launch(void* const* d_in, const int* in_sizes, int n_in,
                              void* d_out, int out_size, void* d_ws, size_t ws_size,
                              hipStream_t stream) {
  // setup_inputs order: x, Wk, Wq, Wv, Wu, bu
  const float* x  = (const float*)d_in[0];
  const float* Wk = (const float*)d_in[1];
  const float* Wq = (const float*)d_in[2];
  const float* Wv = (const float*)d_in[3];
  const float* Wu = (const float*)d_in[4];
  const float* bu = (const float*)d_in[5];

  char* ws = (char*)d_ws;
  const size_t MB1 = 1 << 20;
  unsigned short* xb  = (unsigned short*)(ws + 0);
  unsigned short* wqb = (unsigned short*)(ws + 8  * MB1);
  unsigned short* wkb = (unsigned short*)(ws + 10 * MB1);
  unsigned short* wvb = (unsigned short*)(ws + 12 * MB1);
  unsigned short* wub = (unsigned short*)(ws + 14 * MB1);
  unsigned short* Qb  = (unsigned short*)(ws + 16 * MB1);
  unsigned short* Kb  = (unsigned short*)(ws + 24 * MB1);
  unsigned short* Vt  = (unsigned short*)(ws + 32 * MB1);
  unsigned short* ctx = (unsigned short*)(ws + 40 * MB1);

  cvt_kernel<<<8192, 256, 0, stream>>>(x, Wq, Wk, Wv, Wu, xb, wqb, wkb, wvb, wub);
  gemm_qkv<<<dim3(32, 16), 256, 0, stream>>>(xb, wqb, wkb, wvb, Qb, Kb, Vt);
  attn_kernel<<<dim3(16, 32), 256, 0, stream>>>(Qb, Kb, Vt, ctx);
  gemm_out<<<dim3(32, 16), 256, 0, stream>>>(ctx, wub, bu, (float*)d_out);
}

// Round 10
// 187.588 us; speedup vs baseline: 1.4613x; 1.0699x over previous
//
#include <hip/hip_runtime.h>
#include <hip/hip_bf16.h>

#define HEADS 16
#define SEQ   2048
#define EMB   1024
#define BATCH 2
#define DHEAD 64
#define MTOK  (BATCH * SEQ)   // 4096

typedef __bf16 bf16x8 __attribute__((ext_vector_type(8)));
typedef float  floatx4 __attribute__((ext_vector_type(4)));

__device__ __forceinline__ void gl_lds16(const void* g, void* l) {
  // async global->LDS, 16B/lane; LDS dest = wave-uniform base + lane*16
  __builtin_amdgcn_global_load_lds((__attribute__((address_space(1))) void*)(g),
                                   (__attribute__((address_space(3))) void*)(l), 16, 0, 0);
}

__device__ __forceinline__ unsigned short f2bf(float f) {
  __bf16 h = (__bf16)f;                      // native cvt, RNE
  return __builtin_bit_cast(unsigned short, h);
}

// ---------------- fp32 -> bf16 conversion (x + 4 weights) ----------------
__global__ __launch_bounds__(256) void cvt_kernel(
    const float* __restrict__ x,  const float* __restrict__ wq,
    const float* __restrict__ wk, const float* __restrict__ wv,
    const float* __restrict__ wu,
    unsigned short* __restrict__ xb,  unsigned short* __restrict__ wqb,
    unsigned short* __restrict__ wkb, unsigned short* __restrict__ wvb,
    unsigned short* __restrict__ wub) {
  const int g = blockIdx.x * 256 + threadIdx.x;  // granule of 4 floats
  const int XG = (MTOK * EMB) / 4;               // 1048576
  const int WG = (EMB * EMB) / 4;                // 262144
  const float* src; unsigned short* dst; int off;
  if (g < XG) { src = x; dst = xb; off = g; }
  else {
    int t = g - XG; int wsel = t / WG; off = t - wsel * WG;
    const float* ss[4] = {wq, wk, wv, wu};
    unsigned short* dd[4] = {wqb, wkb, wvb, wub};
    src = ss[wsel]; dst = dd[wsel];
  }
  float4 v = ((const float4*)src)[off];
  ushort4 o;
  o.x = f2bf(v.x); o.y = f2bf(v.y); o.z = f2bf(v.z); o.w = f2bf(v.w);
  ((ushort4*)dst)[off] = o;
}

// ---------------- FUSED QKV projection: q,k,v = x @ {Wq,Wk,Wv}^T ----------------
// BM=128, BN=64, BK=64 (measured-best config, R5/R6): x staged ONCE per k-iter
// for 3 outputs -> 48 MFMA/wave per barrier.
__global__ __launch_bounds__(256) void gemm_qkv(
    const unsigned short* __restrict__ xb,
    const unsigned short* __restrict__ wqb, const unsigned short* __restrict__ wkb,
    const unsigned short* __restrict__ wvb,
    unsigned short* __restrict__ Qb, unsigned short* __restrict__ Kb,
    unsigned short* __restrict__ Vt) {
  constexpr int BM = 128, BN = 64, BK = 64;
  __shared__ unsigned short As[BM * BK];        // XOR-swizzled rows
  __shared__ unsigned short Bs[3 * BN * BK];
  const int m0 = blockIdx.x * BM, n0 = blockIdx.y * BN;
  const int tid = threadIdx.x, w = tid >> 6, lane = tid & 63;
  const int quad = lane >> 4, l16 = lane & 15;
  const int wm = w >> 1, wn = w & 1;
  const int srow = lane >> 3;
  const int scol = ((lane & 7) ^ srow) * 8;
  const unsigned short* Ws[3] = {wqb, wkb, wvb};

  floatx4 acc[3][4][2] = {};

  for (int kt = 0; kt < EMB / BK; ++kt) {
    const int k0 = kt * BK;
#pragma unroll
    for (int i = 0; i < 4; ++i) {
      int r0 = i * 32 + w * 8;
      gl_lds16(xb + (size_t)(m0 + r0 + srow) * EMB + k0 + scol, &As[r0 * BK]);
    }
#pragma unroll
    for (int z = 0; z < 3; ++z)
#pragma unroll
      for (int i = 0; i < 2; ++i) {
        int r0 = i * 32 + w * 8;
        gl_lds16(Ws[z] + (size_t)(n0 + r0 + srow) * EMB + k0 + scol,
                 &Bs[z * (BN * BK) + r0 * BK]);
      }
    __syncthreads();
#pragma unroll
    for (int ks = 0; ks < 2; ++ks) {
      bf16x8 af[4];
#pragma unroll
      for (int mb = 0; mb < 4; ++mb) {
        int ra = wm * 64 + mb * 16 + l16;
        af[mb] = *(const bf16x8*)&As[ra * BK + (((ks * 4 + quad) ^ (ra & 7)) * 8)];
      }
#pragma unroll
      for (int z = 0; z < 3; ++z) {
        bf16x8 bfv[2];
#pragma unroll
        for (int nb = 0; nb < 2; ++nb) {
          int rb = wn * 32 + nb * 16 + l16;
          bfv[nb] = *(const bf16x8*)&Bs[z * (BN * BK) + rb * BK + (((ks * 4 + quad) ^ (rb & 7)) * 8)];
        }
#pragma unroll
        for (int mb = 0; mb < 4; ++mb)
#pragma unroll
          for (int nb = 0; nb < 2; ++nb)
            acc[z][mb][nb] = __builtin_amdgcn_mfma_f32_16x16x32_bf16(af[mb], bfv[nb], acc[z][mb][nb], 0, 0, 0);
      }
    }
    __syncthreads();
  }

  // ---- epilogue: Q (scaled), K, V^T ----
#pragma unroll
  for (int z = 0; z < 2; ++z) {
    unsigned short* C = (z == 0) ? Qb : Kb;
    const float scale = (z == 0) ? 0.180336876f : 1.0f;  // 0.125*log2(e) folded into Q
#pragma unroll
    for (int mb = 0; mb < 4; ++mb) {
#pragma unroll
      for (int nb = 0; nb < 2; ++nb) {
        int n = n0 + wn * 32 + nb * 16 + l16;
#pragma unroll
        for (int r = 0; r < 4; ++r) {
          int m = m0 + wm * 64 + mb * 16 + quad * 4 + r;
          C[(size_t)m * EMB + n] = f2bf(acc[z][mb][nb][r] * scale);
        }
      }
    }
  }
#pragma unroll
  for (int mb = 0; mb < 4; ++mb) {
    int mbase = m0 + wm * 64 + mb * 16 + quad * 4;
    int b = mbase >> 11, s = mbase & (SEQ - 1);
#pragma unroll
    for (int nb = 0; nb < 2; ++nb) {
      int n = n0 + wn * 32 + nb * 16 + l16;
      ushort4 o;
      o.x = f2bf(acc[2][mb][nb][0]); o.y = f2bf(acc[2][mb][nb][1]);
      o.z = f2bf(acc[2][mb][nb][2]); o.w = f2bf(acc[2][mb][nb][3]);
      *(ushort4*)&Vt[((size_t)b * (HEADS * DHEAD) + n) * SEQ + s] = o;
    }
  }
}

// ---------------- flash-style causal attention, v8: XCD-local K/V ----------------
// Identical compute to R5 (66.8 us) but grid swapped to (bh=32, pair=16):
// same-bh blocks get linear ids bh+32k -> XCD (bh%8) -> all 16 blocks sharing
// one bh's K/V (512 KB) land on ONE XCD; K/V stays L2-resident across the
// whole dispatch instead of being re-fetched by 8 XCDs (125 MB -> ~35 MB).
__global__ __launch_bounds__(256) void attn_kernel(
    const unsigned short* __restrict__ Qb, const unsigned short* __restrict__ Kb,
    const unsigned short* __restrict__ Vt, unsigned short* __restrict__ ctx) {
  constexpr int KT = 128;
  constexpr int PST = KT + 8;                     // padded row stride (ushorts)
  __shared__ unsigned short Ks[KT * DHEAD];       // fragment order: (f*64+lane)*8
  __shared__ unsigned short Vs[DHEAD * KT];       // fragment order
  __shared__ __bf16 Ps[4 * 16 * PST];             // per-wave [16][PST]
  const int bh = blockIdx.x, pair = blockIdx.y;   // SWAPPED vs R5 (XCD locality)
  const int b = bh >> 4, h = bh & 15;
  const int tid = threadIdx.x, w = tid >> 6, lane = tid & 63;
  const int quad = lane >> 4, l16 = lane & 15;

  const unsigned short* Kbh = Kb + (size_t)b * SEQ * EMB + h * DHEAD;
  const unsigned short* Vbh = Vt + (size_t)bh * DHEAD * SEQ;
  __bf16* Pw = &Ps[w * (16 * PST)];

  // per-lane staging coordinates (chunk c = i*256 + tid)
  int kq[4], kd[4], vd[4], vk[4];
#pragma unroll
  for (int i = 0; i < 4; ++i) {
    int c = i * 256 + tid;
    kq[i] = ((c >> 6) & 7) * 16 + (c & 15);           // key row within tile (K)
    kd[i] = ((c >> 9) << 5) + (((c >> 4) & 3) << 3);  // d offset (K)
    vd[i] = (((c >> 6) & 3) << 4) + (c & 15);         // d row (V^T)
    vk[i] = (((c >> 8) & 3) << 5) + (((c >> 4) & 3) << 3);  // key offset (V^T)
  }

  for (int pi = 0; pi < 2; ++pi) {
    const int qt = pi ? (31 - pair) : pair;
    const int q0 = qt * 64;
    const int myrow = q0 + w * 16 + quad * 4;     // this lane's 4 rows start

    const size_t qrow = (size_t)(b * SEQ + q0 + w * 16 + l16) * EMB + h * DHEAD;
    bf16x8 qf[2];
    qf[0] = *(const bf16x8*)&Qb[qrow + quad * 8];
    qf[1] = *(const bf16x8*)&Qb[qrow + 32 + quad * 8];

    float lsum[4] = {0.0f, 0.0f, 0.0f, 0.0f};     // lane-local partial row sums
    floatx4 acc_o[4] = {};

    const int nkt = (qt + 2) >> 1;                // ceil((qt+1)*64/128)
    for (int ktile = 0; ktile < nkt; ++ktile) {
      const int kt0 = ktile * KT;
      // ---- stage K (16KB) + V (16KB) in fragment order ----
#pragma unroll
      for (int i = 0; i < 4; ++i) {
        gl_lds16(Kbh + (size_t)(kt0 + kq[i]) * EMB + kd[i], &Ks[(i * 256 + w * 64) * 8]);
        gl_lds16(Vbh + (size_t)vd[i] * SEQ + kt0 + vk[i], &Vs[(i * 256 + w * 64) * 8]);
      }
      __syncthreads();

      // ---- S = Q K^T : 16 rows x 128 keys per wave ----
      floatx4 accs[8] = {};
#pragma unroll
      for (int ks = 0; ks < 2; ++ks)
#pragma unroll
        for (int nb = 0; nb < 8; ++nb) {
          bf16x8 kf = *(const bf16x8*)&Ks[((ks * 8 + nb) * 64 + lane) * 8];
          accs[nb] = __builtin_amdgcn_mfma_f32_16x16x32_bf16(qf[ks], kf, accs[nb], 0, 0, 0);
        }

      // ---- causal mask (diagonal tile only) ----
      if (ktile == nkt - 1) {
#pragma unroll
        for (int nb = 0; nb < 8; ++nb) {
          int col = kt0 + nb * 16 + l16;
#pragma unroll
          for (int r = 0; r < 4; ++r)
            if (col > myrow + r) accs[nb][r] = -1e30f;
        }
      }

      // ---- p = exp2(s) (fixed shift, exact — see R5), accumulate l, stash P ----
#pragma unroll
      for (int r = 0; r < 4; ++r) {
#pragma unroll
        for (int nb = 0; nb < 8; ++nb) {
          float pe = exp2f(accs[nb][r]);
          Pw[(quad * 4 + r) * PST + nb * 16 + l16] = (__bf16)pe;
          lsum[r] += pe;
        }
      }

      // ---- O += P V  (Ps is wave-private: no barrier needed) ----
#pragma unroll
      for (int ks = 0; ks < 4; ++ks) {
        bf16x8 pf = *(const bf16x8*)&Pw[l16 * PST + ks * 32 + quad * 8];
#pragma unroll
        for (int nb = 0; nb < 4; ++nb) {
          bf16x8 vf = *(const bf16x8*)&Vs[((ks * 4 + nb) * 64 + lane) * 8];
          acc_o[nb] = __builtin_amdgcn_mfma_f32_16x16x32_bf16(pf, vf, acc_o[nb], 0, 0, 0);
        }
      }
      __syncthreads();   // all waves done with Ks/Vs before next staging
    }

    // ---- reduce l over the 16-lane group (disjoint key subsets), then write ----
#pragma unroll
    for (int r = 0; r < 4; ++r) {
      float rs = lsum[r];
      rs += __shfl_xor(rs, 1);
      rs += __shfl_xor(rs, 2);
      rs += __shfl_xor(rs, 4);
      rs += __shfl_xor(rs, 8);
      float inv = 1.0f / rs;
      size_t base = (size_t)(b * SEQ + myrow + r) * EMB + h * DHEAD;
#pragma unroll
      for (int nb = 0; nb < 4; ++nb)
        ctx[base + nb * 16 + l16] = f2bf(acc_o[nb][r] * inv);
    }
  }
}

// ---------------- output projection: out = ctx @ Wu^T + bu (fp32 out) ----------------
// 128x64 tile, BK=64 swizzled (measured-best); wave tile 64x32 (4x2 MFMA grid).
__global__ __launch_bounds__(256) void gemm_out(
    const unsigned short* __restrict__ ctx, const unsigned short* __restrict__ wub,
    const float* __restrict__ bu, float* __restrict__ out) {
  constexpr int BM = 128, BN = 64, BK = 64;
  __shared__ unsigned short As[BM * BK];
  __shared__ unsigned short Bs[BN * BK];
  const int m0 = blockIdx.x * BM, n0 = blockIdx.y * BN;
  const int tid = threadIdx.x, w = tid >> 6, lane = tid & 63;
  const int quad = lane >> 4, l16 = lane & 15;
  const int wm = w >> 1, wn = w & 1;
  const int srow = lane >> 3;
  const int scol = ((lane & 7) ^ srow) * 8;

  floatx4 acc[4][2] = {};

  for (int kt = 0; kt < EMB / BK; ++kt) {
    const int k0 = kt * BK;
#pragma unroll
    for (int i = 0; i < 4; ++i) {
      int r0 = i * 32 + w * 8;
      gl_lds16(ctx + (size_t)(m0 + r0 + srow) * EMB + k0 + scol, &As[r0 * BK]);
    }
#pragma unroll
    for (int i = 0; i < 2; ++i) {
      int r0 = i * 32 + w * 8;
      gl_lds16(wub + (size_t)(n0 + r0 + srow) * EMB + k0 + scol, &Bs[r0 * BK]);
    }
    __syncthreads();
    bf16x8 af[4][2], bfv[2][2];
#pragma unroll
    for (int mb = 0; mb < 4; ++mb) {
      int ra = wm * 64 + mb * 16 + l16;
#pragma unroll
      for (int ks = 0; ks < 2; ++ks)
        af[mb][ks] = *(const bf16x8*)&As[ra * BK + (((ks * 4 + quad) ^ (ra & 7)) * 8)];
    }
#pragma unroll
    for (int nb = 0; nb < 2; ++nb) {
      int rb = wn * 32 + nb * 16 + l16;
#pragma unroll
      for (int ks = 0; ks < 2; ++ks)
        bfv[nb][ks] = *(const bf16x8*)&Bs[rb * BK + (((ks * 4 + quad) ^ (rb & 7)) * 8)];
    }
#pragma unroll
    for (int ks = 0; ks < 2; ++ks)
#pragma unroll
      for (int mb = 0; mb < 4; ++mb)
#pragma unroll
        for (int nb = 0; nb < 2; ++nb)
          acc[mb][nb] = __builtin_amdgcn_mfma_f32_16x16x32_bf16(af[mb][ks], bfv[nb][ks], acc[mb][nb], 0, 0, 0);
    __syncthreads();
  }

#pragma unroll
  for (int mb = 0; mb < 4; ++mb) {
#pragma unroll
    for (int nb = 0; nb < 2; ++nb) {
      int n = n0 + wn * 32 + nb * 16 + l16;
      float bias = bu[n];
#pragma unroll
      for (int r = 0; r < 4; ++r) {
        int m = m0 + wm * 64 + mb * 16 + quad * 4 + r;
        out[(size_t)m * EMB + n] = acc[mb][nb][r] + bias;
      }
    }
  }
}

extern "C" void kernel_launch(void* const* d_in, const int* in_sizes, int n_in,
                              void* d_out, int out_size, void* d_ws, size_t ws_size,
                              hipStream_t stream) {
  // setup_inputs order: x, Wk, Wq, Wv, Wu, bu
  const float* x  = (const float*)d_in[0];
  const float* Wk = (const float*)d_in[1];
  const float* Wq = (const float*)d_in[2];
  const float* Wv = (const float*)d_in[3];
  const float* Wu = (const float*)d_in[4];
  const float* bu = (const float*)d_in[5];

  char* ws = (char*)d_ws;
  const size_t MB1 = 1 << 20;
  unsigned short* xb  = (unsigned short*)(ws + 0);
  unsigned short* wqb = (unsigned short*)(ws + 8  * MB1);
  unsigned short* wkb = (unsigned short*)(ws + 10 * MB1);
  unsigned short* wvb = (unsigned short*)(ws + 12 * MB1);
  unsigned short* wub = (unsigned short*)(ws + 14 * MB1);
  unsigned short* Qb  = (unsigned short*)(ws + 16 * MB1);
  unsigned short* Kb  = (unsigned short*)(ws + 24 * MB1);
  unsigned short* Vt  = (unsigned short*)(ws + 32 * MB1);
  unsigned short* ctx = (unsigned short*)(ws + 40 * MB1);

  cvt_kernel<<<8192, 256, 0, stream>>>(x, Wq, Wk, Wv, Wu, xb, wqb, wkb, wvb, wub);
  gemm_qkv<<<dim3(32, 16), 256, 0, stream>>>(xb, wqb, wkb, wvb, Qb, Kb, Vt);
  attn_kernel<<<dim3(32, 16), 256, 0, stream>>>(Qb, Kb, Vt, ctx);
  gemm_out<<<dim3(32, 16), 256, 0, stream>>>(ctx, wub, bu, (float*)d_out);
}